// Round 4
// baseline (2586.076 us; speedup 1.0000x reference)
//
#include <hip/hip_runtime.h>
#include <math.h>

#define XS 61  // padded x row stride in floats (breaks the 2-row gather stride conflict)

namespace {
constexpr int TAB_N = 59 * 60 * 120;   // 424800 entries, u16 byte offsets
}

// Build gather table: tab[(jj*60+ri)*120 + c] = byte offset into padded s.x
// for pp row rr = ri*59+jj, MLP input column c (faithful row-major-flatten quirk):
//   p = rr*120+c ; f = p/3540 ; e = p%3540 ; i = e/59 ; j = e%59
//   col = f<60 ? i : (j<i ? j : j+1) ; ft = f%60 ; off = (ft*61+col)*4
__global__ __launch_bounds__(256) void build_tab_kernel(unsigned short* __restrict__ tab) {
  int t = blockIdx.x * 256 + threadIdx.x;
  if (t >= TAB_N) return;
  unsigned c = (unsigned)t % 120u;
  unsigned rem = (unsigned)t / 120u;
  unsigned ri = rem % 60u;
  unsigned jj = rem / 60u;
  unsigned rr = ri * 59u + jj;
  unsigned p = rr * 120u + c;
  unsigned f = p / 3540u, e = p - f * 3540u;
  unsigned i = e / 59u, j = e - i * 59u;
  unsigned col = (f < 60u) ? i : ((j < i) ? j : (j + 1u));
  unsigned ft = (f < 60u) ? f : (f - 60u);
  tab[t] = (unsigned short)((ft * (unsigned)XS + col) * 4u);
}

struct __align__(16) Smem {
  float x[60 * XS];     // 3660 (padded rows)
  float hid[3600];      // out-MLP hidden [row][60]
  float w2ot[24 * 60];  // W2_o transposed [o][h]
  float ebar[60 * 20];  // Ebar [i][o]
  float y[72];
  float osum[24];
};

// a[h] += v * w[h], weights are wave-uniform global (compiler -> s_load + v_fmac)
__device__ __forceinline__ void fma60(float (&a)[60], float v, const float* __restrict__ w) {
#pragma unroll
  for (int h = 0; h < 60; ++h) a[h] = fmaf(v, w[h], a[h]);
}

// relu(a) then acc[o] += sum_h a[h]*w2[h*20+o]  (w2 wave-uniform global)
__device__ __forceinline__ void relu_stage2(float (&a)[60], float (&acc)[20],
                                            const float* __restrict__ w2) {
#pragma unroll
  for (int h = 0; h < 60; ++h) a[h] = fmaxf(a[h], 0.f);
#pragma unroll
  for (int o = 0; o < 20; ++o) {
    float t0 = 0.f, t1 = 0.f, t2 = 0.f, t3 = 0.f;
#pragma unroll
    for (int h = 0; h < 60; h += 4) {
      t0 = fmaf(a[h + 0], w2[(h + 0) * 20 + o], t0);
      t1 = fmaf(a[h + 1], w2[(h + 1) * 20 + o], t1);
      t2 = fmaf(a[h + 2], w2[(h + 2) * 20 + o], t2);
      t3 = fmaf(a[h + 3], w2[(h + 3) * 20 + o], t3);
    }
    acc[o] += (t0 + t1) + (t2 + t3);
  }
}

__global__ __launch_bounds__(256, 2) void fused_kernel(
    const float* __restrict__ x, const float* __restrict__ y,
    const float* __restrict__ W1pp, const float* __restrict__ B1pp,
    const float* __restrict__ W2pp, const float* __restrict__ B2pp,
    const float* __restrict__ W1pv, const float* __restrict__ B1pv,
    const float* __restrict__ W2pv, const float* __restrict__ B2pv,
    const float* __restrict__ W1o, const float* __restrict__ B1o,
    const float* __restrict__ W2o, const float* __restrict__ B2o,
    const float* __restrict__ Wc, const float* __restrict__ Bc,
    const unsigned short* __restrict__ tab,
    float* __restrict__ out)
{
  __shared__ Smem s;
  const int b = blockIdx.x;
  const int tid = threadIdx.x;
  const int w = tid >> 6;       // wave 0..3
  const int lane = tid & 63;

  // ---- staging ----
  for (int k = tid; k < 3600; k += 256) {
    int row = k / 60, col = k - row * 60;
    s.x[row * XS + col] = x[b * 3600 + k];
  }
  if (tid < 70) s.y[tid] = y[b * 70 + tid];
  for (int k = tid; k < 1440; k += 256) {
    int h = k / 24, o = k - h * 24;
    s.w2ot[o * 60 + h] = W2o[k];
  }
  for (int k = tid; k < 1200; k += 256) s.ebar[k] = 0.f;
  if (tid < 24) s.osum[tid] = 60.f * B2o[tid];   // bias summed over 60 rows
  __syncthreads();

  // ---- particle-particle branch: lane = receiver ri, wave w owns edges jj in [w*15, ...) ----
  if (lane < 60) {
    const int ri = lane;
    const int cnt = (w < 3) ? 15 : 14;            // 59 = 15+15+15+14
    float acc[20];
#pragma unroll
    for (int o = 0; o < 20; ++o) acc[o] = (float)cnt * B2pp[o];

    for (int q = 0; q < cnt; ++q) {
      const int jj = w * 15 + q;
      const unsigned short* tp = tab + (jj * 60 + ri) * 120;
      float a[60];
#pragma unroll
      for (int h = 0; h < 60; ++h) a[h] = B1pp[h];

      const char* xb = reinterpret_cast<const char*>(s.x);
      for (int c8 = 0; c8 < 15; ++c8) {
        uint4 cur = *reinterpret_cast<const uint4*>(tp + c8 * 8);   // 8 u16 offsets
        float v0 = *reinterpret_cast<const float*>(xb + (cur.x & 0xffffu));
        float v1 = *reinterpret_cast<const float*>(xb + (cur.x >> 16));
        float v2 = *reinterpret_cast<const float*>(xb + (cur.y & 0xffffu));
        float v3 = *reinterpret_cast<const float*>(xb + (cur.y >> 16));
        float v4 = *reinterpret_cast<const float*>(xb + (cur.z & 0xffffu));
        float v5 = *reinterpret_cast<const float*>(xb + (cur.z >> 16));
        float v6 = *reinterpret_cast<const float*>(xb + (cur.w & 0xffffu));
        float v7 = *reinterpret_cast<const float*>(xb + (cur.w >> 16));
        const float* wb = W1pp + c8 * 8 * 60;
        fma60(a, v0, wb);
        fma60(a, v1, wb + 60);
        fma60(a, v2, wb + 120);
        fma60(a, v3, wb + 180);
        fma60(a, v4, wb + 240);
        fma60(a, v5, wb + 300);
        fma60(a, v6, wb + 360);
        fma60(a, v7, wb + 420);
      }
      relu_stage2(a, acc, W2pp);
    }
#pragma unroll
    for (int o = 0; o < 20; ++o) atomicAdd(&s.ebar[ri * 20 + o], acc[o]);
  }

  // ---- particle-vertex branch: lane = particle i, wave w owns vertices v in [w*4, ...) ----
  if (lane < 60) {
    const int i = lane;
    const int vcnt = (w < 3) ? 4 : 2;             // 14 = 4+4+4+2
    float acc[20];
#pragma unroll
    for (int o = 0; o < 20; ++o) acc[o] = (float)vcnt * B2pv[o];

    for (int q = 0; q < vcnt; ++q) {
      const int vv = w * 4 + q;
      float a[60];
#pragma unroll
      for (int h = 0; h < 60; ++h) a[h] = B1pv[h];
      for (int c = 0; c < 60; ++c) fma60(a, s.x[c * XS + i], W1pv + c * 60);
#pragma unroll
      for (int c = 0; c < 5; ++c) fma60(a, s.y[c * 14 + vv], W1pv + (60 + c) * 60);
      relu_stage2(a, acc, W2pv);
    }
#pragma unroll
    for (int o = 0; o < 20; ++o) atomicAdd(&s.ebar[i * 20 + o], acc[o]);
  }

  __syncthreads();   // ebar complete

  // ---- output MLP hidden: lane = row r, wave w = hidden chunk [w*15, w*15+15) ----
  if (lane < 60) {
    const int r = lane;
    const int k0 = w * 15;
    float a15[15];
#pragma unroll
    for (int k = 0; k < 15; ++k) a15[k] = B1o[k0 + k];
    for (int c = 0; c < 60; ++c) {
      float v = s.x[r * XS + c];
      const float* wr = W1o + c * 60 + k0;
#pragma unroll
      for (int k = 0; k < 15; ++k) a15[k] = fmaf(v, wr[k], a15[k]);
    }
    for (int c = 0; c < 20; ++c) {
      float v = s.ebar[r * 20 + c];
      const float* wr = W1o + (60 + c) * 60 + k0;
#pragma unroll
      for (int k = 0; k < 15; ++k) a15[k] = fmaf(v, wr[k], a15[k]);
    }
#pragma unroll
    for (int k = 0; k < 15; ++k) s.hid[r * 60 + k0 + k] = fmaxf(a15[k], 0.f);
  }
  __syncthreads();

  // ---- output stage 2 + row-sum: 1440 (row,o) dots, atomically reduced into osum[o] ----
  for (int idx = tid; idx < 1440; idx += 256) {
    const int r = idx / 24, o = idx - r * 24;
    const float4* hp = reinterpret_cast<const float4*>(&s.hid[r * 60]);
    const float4* wp = reinterpret_cast<const float4*>(&s.w2ot[o * 60]);
    float t0 = 0.f, t1 = 0.f, t2 = 0.f, t3 = 0.f;
#pragma unroll
    for (int h4 = 0; h4 < 15; ++h4) {
      float4 hv = hp[h4], wv = wp[h4];
      t0 = fmaf(hv.x, wv.x, t0);
      t1 = fmaf(hv.y, wv.y, t1);
      t2 = fmaf(hv.z, wv.z, t2);
      t3 = fmaf(hv.w, wv.w, t3);
    }
    atomicAdd(&s.osum[o], (t0 + t1) + (t2 + t3));
  }
  __syncthreads();

  if (tid == 0) {
    float sd = Bc[0];
#pragma unroll
    for (int o = 0; o < 24; ++o) sd = fmaf(s.osum[o], Wc[o], sd);
    out[b] = 1.f / (1.f + expf(-sd));
  }
}

extern "C" void kernel_launch(void* const* d_in, const int* in_sizes, int n_in,
                              void* d_out, int out_size, void* d_ws, size_t ws_size,
                              hipStream_t stream) {
  const float* x     = (const float*)d_in[0];
  const float* y     = (const float*)d_in[1];
  const float* W1_pp = (const float*)d_in[2];
  const float* b1_pp = (const float*)d_in[3];
  const float* W2_pp = (const float*)d_in[4];
  const float* b2_pp = (const float*)d_in[5];
  const float* W1_pv = (const float*)d_in[6];
  const float* b1_pv = (const float*)d_in[7];
  const float* W2_pv = (const float*)d_in[8];
  const float* b2_pv = (const float*)d_in[9];
  const float* W1_o  = (const float*)d_in[10];
  const float* b1_o  = (const float*)d_in[11];
  const float* W2_o  = (const float*)d_in[12];
  const float* b2_o  = (const float*)d_in[13];
  const float* Wc    = (const float*)d_in[14];
  const float* bc    = (const float*)d_in[15];
  float* out = (float*)d_out;
  unsigned short* tab = (unsigned short*)d_ws;   // 424800 u16 = 849.6 KB

  const int Bb = in_sizes[0] / 3600;             // 1024

  build_tab_kernel<<<(TAB_N + 255) / 256, 256, 0, stream>>>(tab);
  fused_kernel<<<Bb, 256, 0, stream>>>(x, y,
      W1_pp, b1_pp, W2_pp, b2_pp,
      W1_pv, b1_pv, W2_pv, b2_pv,
      W1_o, b1_o, W2_o, b2_o,
      Wc, bc, tab, out);
}

// Round 5
// 347.415 us; speedup vs baseline: 7.4438x; 7.4438x over previous
//
#include <hip/hip_runtime.h>
#include <hip/hip_bf16.h>
#include <math.h>

typedef __attribute__((ext_vector_type(8))) short short8;
typedef __attribute__((ext_vector_type(4))) float f32x4;

namespace {
// ---- LDS arena word-offsets (u16 word offsets stored in tables) ----
constexpr int XP = 61;          // padded x row stride
constexpr int EB0 = 3660;       // ebar [60][20]
constexpr int Y0 = 4860;        // y [5][14]
constexpr int ZSLOT = 4930;     // zero word
constexpr int ARENA_W = 4931;

// ---- ws byte offsets ----
constexpr int NTAB_PP = 222 * 4 * 64 * 8;   // 454656
constexpr int NTAB_PV = 53 * 3 * 64 * 8;    // 81408
constexpr int NTAB_O  = 4 * 3 * 64 * 8;     // 6144
constexpr int TABPP_B = 0;
constexpr int TABPV_B = 909312;
constexpr int TABO_B  = 1072128;
constexpr int WPP1_B  = 1084416;  // 16 frags * 64 lanes * 16B
constexpr int WPP2_B  = 1100800;  //  4 frags
constexpr int WPV1_B  = 1104896;  // 12 frags
constexpr int WPV2_B  = 1117184;  //  4 frags
constexpr int WO1_B   = 1121280;  // 12 frags
constexpr int WO2_B   = 1133568;  //  4 frags
constexpr int BIAS_B  = 1137664;  // 288 f32 (padded biases)
}

__device__ __forceinline__ short f2bfs(float f) {
  __hip_bfloat16 h = __float2bfloat16(f);
  short s;
  __builtin_memcpy(&s, &h, 2);
  return s;
}

// ---------------- init: gather tables (u16 word offsets into arena) ----------------
__global__ __launch_bounds__(256) void build_tables(char* wsb) {
  int t = blockIdx.x * 256 + threadIdx.x;
  unsigned short* tpp = (unsigned short*)(wsb + TABPP_B);
  unsigned short* tpv = (unsigned short*)(wsb + TABPV_B);
  unsigned short* tou = (unsigned short*)(wsb + TABO_B);
  if (t < NTAB_PP) {
    int j = t & 7, l = (t >> 3) & 63, blk = t >> 9;
    int ks = blk & 3, mt = blk >> 2;
    int rr = mt * 16 + (l & 15), k = ks * 32 + (l >> 4) * 8 + j;
    unsigned off = ZSLOT;
    if (rr < 3540 && k < 120) {
      unsigned p = (unsigned)rr * 120u + (unsigned)k;
      unsigned f = p / 3540u, e = p - f * 3540u;
      unsigned i = e / 59u, jj = e - i * 59u;
      unsigned col = (f < 60u) ? i : ((jj < i) ? jj : jj + 1u);
      unsigned ft = (f < 60u) ? f : f - 60u;
      off = ft * (unsigned)XP + col;
    }
    tpp[t] = (unsigned short)off;
    return;
  }
  t -= NTAB_PP;
  if (t < NTAB_PV) {
    int j = t & 7, l = (t >> 3) & 63, blk = t >> 9;
    int ks = blk % 3, mt = blk / 3;
    int tt = mt * 16 + (l & 15), k = ks * 32 + (l >> 4) * 8 + j;
    unsigned off = ZSLOT;
    if (tt < 840 && k < 65) {
      int i = tt / 14, v = tt - i * 14;
      off = (k < 60) ? (unsigned)(k * XP + i) : (unsigned)(Y0 + (k - 60) * 14 + v);
    }
    tpv[t] = (unsigned short)off;
    return;
  }
  t -= NTAB_PV;
  if (t < NTAB_O) {
    int j = t & 7, l = (t >> 3) & 63, blk = t >> 9;
    int ks = blk % 3, mt = blk / 3;
    int r = mt * 16 + (l & 15), k = ks * 32 + (l >> 4) * 8 + j;
    unsigned off = ZSLOT;
    if (r < 60 && k < 80)
      off = (k < 60) ? (unsigned)(r * XP + k) : (unsigned)(EB0 + r * 20 + (k - 60));
    tou[t] = (unsigned short)off;
  }
}

// ---------------- init: weight fragments (bf16, B-layout) + padded biases ----------------
// B-frag: lane l holds B[k = ks*32 + (l>>4)*8 + j][n = nt*16 + (l&15)], j=2d lo / 2d+1 hi of dword d.
__global__ __launch_bounds__(256) void build_wfrag(char* wsb,
    const float* W1pp, const float* W2pp, const float* W1pv, const float* W2pv,
    const float* W1o, const float* W2o,
    const float* b1pp, const float* b2pp, const float* b1pv, const float* b2pv,
    const float* b1o, const float* b2o) {
  int t = blockIdx.x * 256 + threadIdx.x;
  if (t < 13312) {
    const float* W; int Kt, Nt, NTt; unsigned* dst; int local;
    if (t < 4096)       { W = W1pp; Kt = 120; Nt = 60; NTt = 4; dst = (unsigned*)(wsb + WPP1_B); local = t; }
    else if (t < 5120)  { W = W2pp; Kt = 60;  Nt = 20; NTt = 2; dst = (unsigned*)(wsb + WPP2_B); local = t - 4096; }
    else if (t < 8192)  { W = W1pv; Kt = 65;  Nt = 60; NTt = 4; dst = (unsigned*)(wsb + WPV1_B); local = t - 5120; }
    else if (t < 9216)  { W = W2pv; Kt = 60;  Nt = 20; NTt = 2; dst = (unsigned*)(wsb + WPV2_B); local = t - 8192; }
    else if (t < 12288) { W = W1o;  Kt = 80;  Nt = 60; NTt = 4; dst = (unsigned*)(wsb + WO1_B);  local = t - 9216; }
    else                { W = W2o;  Kt = 60;  Nt = 24; NTt = 2; dst = (unsigned*)(wsb + WO2_B);  local = t - 12288; }
    int d = local & 3, l = (local >> 2) & 63, rest = local >> 8;
    int nt = rest % NTt, ks = rest / NTt;
    int k = ks * 32 + (l >> 4) * 8 + 2 * d, n = nt * 16 + (l & 15);
    float v0 = (k < Kt && n < Nt) ? W[k * Nt + n] : 0.f;
    float v1 = (k + 1 < Kt && n < Nt) ? W[(k + 1) * Nt + n] : 0.f;
    unsigned u0 = (unsigned short)f2bfs(v0);
    unsigned u1 = (unsigned short)f2bfs(v1);
    dst[local] = u0 | (u1 << 16);
    return;
  }
  t -= 13312;
  if (t < 288) {
    float* bd = (float*)(wsb + BIAS_B);
    float v = 0.f;
    if (t < 64)       { if (t < 60) v = b1pp[t]; }
    else if (t < 96)  { int n = t - 64;  if (n < 20) v = b2pp[n]; }
    else if (t < 160) { int n = t - 96;  if (n < 60) v = b1pv[n]; }
    else if (t < 192) { int n = t - 160; if (n < 20) v = b2pv[n]; }
    else if (t < 256) { int n = t - 192; if (n < 60) v = b1o[n]; }
    else              { int n = t - 256; if (n < 24) v = b2o[n]; }
    bd[t] = v;
  }
}

// ---------------- one M-tile: gathered-A stage1 MFMA -> relu -> stage2 MFMA ----------------
// A-frag: lane l holds A[m = l&15][k = (l>>4)*8 + j]; C/D: col = l&15, row = (l>>4)*4 + reg.
template <int NKS>
__device__ __forceinline__ void mlp_tile(
    int mt, int lane, const uint4* __restrict__ tab,
    const short8 (&bf1)[NKS * 4], const short8 (&bf2)[4],
    const float* __restrict__ biasf, int b1off, int b2off,
    const float* arena, short (*hrow)[72], f32x4 (&a2)[2]) {
  const int cl = lane & 15, qq = lane >> 4;
  f32x4 acc[4];
#pragma unroll
  for (int nt = 0; nt < 4; ++nt) {
    float bv = biasf[b1off + nt * 16 + cl];
    acc[nt] = (f32x4){bv, bv, bv, bv};
  }
#pragma unroll
  for (int ks = 0; ks < NKS; ++ks) {
    uint4 tw = tab[(mt * NKS + ks) * 64 + lane];
    float g0 = arena[tw.x & 0xffffu];
    float g1 = arena[tw.x >> 16];
    float g2 = arena[tw.y & 0xffffu];
    float g3 = arena[tw.y >> 16];
    float g4 = arena[tw.z & 0xffffu];
    float g5 = arena[tw.z >> 16];
    float g6 = arena[tw.w & 0xffffu];
    float g7 = arena[tw.w >> 16];
    short8 af;
    af[0] = f2bfs(g0); af[1] = f2bfs(g1); af[2] = f2bfs(g2); af[3] = f2bfs(g3);
    af[4] = f2bfs(g4); af[5] = f2bfs(g5); af[6] = f2bfs(g6); af[7] = f2bfs(g7);
#pragma unroll
    for (int nt = 0; nt < 4; ++nt)
      acc[nt] = __builtin_amdgcn_mfma_f32_16x16x32_bf16(af, bf1[ks * 4 + nt], acc[nt], 0, 0, 0);
  }
  // relu -> per-wave H tile (bf16, row-padded to 72 shorts = 144B)
#pragma unroll
  for (int nt = 0; nt < 4; ++nt)
#pragma unroll
    for (int r = 0; r < 4; ++r)
      hrow[qq * 4 + r][nt * 16 + cl] = f2bfs(fmaxf(acc[nt][r], 0.f));
  // stage 2: E = relu(H) @ W2  (K=64 -> 2 ksteps, N=32 -> 2 ntiles)
#pragma unroll
  for (int nt = 0; nt < 2; ++nt) {
    float bv = biasf[b2off + nt * 16 + cl];
    a2[nt] = (f32x4){bv, bv, bv, bv};
  }
#pragma unroll
  for (int k2 = 0; k2 < 2; ++k2) {
    short8 af2 = *(const short8*)&hrow[cl][k2 * 32 + qq * 8];
#pragma unroll
    for (int nt = 0; nt < 2; ++nt)
      a2[nt] = __builtin_amdgcn_mfma_f32_16x16x32_bf16(af2, bf2[k2 * 2 + nt], a2[nt], 0, 0, 0);
  }
}

// ---------------- fused kernel: one block per batch element ----------------
__global__ __launch_bounds__(256, 2) void fused_kernel(
    const float* __restrict__ x, const float* __restrict__ y,
    const float* __restrict__ Wc, const float* __restrict__ Bc,
    const char* __restrict__ wsb, float* __restrict__ out) {
  __shared__ float arena[ARENA_W];
  __shared__ short hlds[4][16][72];
  __shared__ float osum[24];

  const int b = blockIdx.x;
  const int tid = threadIdx.x;
  const int w = tid >> 6;
  const int lane = tid & 63;
  const int cl = lane & 15, qq = lane >> 4, q4 = (lane >> 4) * 4;

  // ---- stage inputs ----
  for (int k = tid; k < 3600; k += 256) {
    int r = k / 60, c = k - r * 60;
    arena[r * XP + c] = x[(size_t)b * 3600 + k];
  }
  if (tid < 70) arena[Y0 + tid] = y[(size_t)b * 70 + tid];
  for (int k = tid; k < 1200; k += 256) arena[EB0 + k] = 0.f;
  if (tid == 0) arena[ZSLOT] = 0.f;
  if (tid < 24) osum[tid] = 0.f;
  __syncthreads();

  const float* biasf = (const float*)(wsb + BIAS_B);

  // ================= particle-particle =================
  {
    const short8* wf1 = (const short8*)(wsb + WPP1_B);
    const short8* wf2 = (const short8*)(wsb + WPP2_B);
    short8 bf1[16], bf2[4];
#pragma unroll
    for (int i = 0; i < 16; ++i) bf1[i] = wf1[i * 64 + lane];
#pragma unroll
    for (int i = 0; i < 4; ++i) bf2[i] = wf2[i * 64 + lane];
    const uint4* tab = (const uint4*)(wsb + TABPP_B);

    for (int mt = w; mt < 222; mt += 4) {
      f32x4 a2[2];
      mlp_tile<4>(mt, lane, tab, bf1, bf2, biasf, 0, 64, arena, hlds[w], a2);
      // scatter: ri = rr/59
      int rb = mt * 16 + q4;
      int riA = rb / 59, riB = (rb + 3) / 59;
#pragma unroll
      for (int nt = 0; nt < 2; ++nt) {
        int col = nt * 16 + cl;
        if (col < 20) {
          if (riA == riB && rb + 3 < 3540) {
            atomicAdd(&arena[EB0 + riA * 20 + col],
                      a2[nt][0] + a2[nt][1] + a2[nt][2] + a2[nt][3]);
          } else {
#pragma unroll
            for (int r = 0; r < 4; ++r) {
              int rr = rb + r;
              if (rr < 3540) atomicAdd(&arena[EB0 + (rr / 59) * 20 + col], a2[nt][r]);
            }
          }
        }
      }
    }
  }

  // ================= particle-vertex =================
  {
    const short8* wf1 = (const short8*)(wsb + WPV1_B);
    const short8* wf2 = (const short8*)(wsb + WPV2_B);
    short8 bf1[12], bf2[4];
#pragma unroll
    for (int i = 0; i < 12; ++i) bf1[i] = wf1[i * 64 + lane];
#pragma unroll
    for (int i = 0; i < 4; ++i) bf2[i] = wf2[i * 64 + lane];
    const uint4* tab = (const uint4*)(wsb + TABPV_B);

    for (int mt = w; mt < 53; mt += 4) {
      f32x4 a2[2];
      mlp_tile<3>(mt, lane, tab, bf1, bf2, biasf, 96, 160, arena, hlds[w], a2);
      int rb = mt * 16 + q4;
      int riA = rb / 14, riB = (rb + 3) / 14;
#pragma unroll
      for (int nt = 0; nt < 2; ++nt) {
        int col = nt * 16 + cl;
        if (col < 20) {
          if (riA == riB && rb + 3 < 840) {
            atomicAdd(&arena[EB0 + riA * 20 + col],
                      a2[nt][0] + a2[nt][1] + a2[nt][2] + a2[nt][3]);
          } else {
#pragma unroll
            for (int r = 0; r < 4; ++r) {
              int tt = rb + r;
              if (tt < 840) atomicAdd(&arena[EB0 + (tt / 14) * 20 + col], a2[nt][r]);
            }
          }
        }
      }
    }
  }

  __syncthreads();  // ebar complete

  // ================= output MLP (60 rows = 4 tiles, one per wave) =================
  {
    const short8* wf1 = (const short8*)(wsb + WO1_B);
    const short8* wf2 = (const short8*)(wsb + WO2_B);
    short8 bf1[12], bf2[4];
#pragma unroll
    for (int i = 0; i < 12; ++i) bf1[i] = wf1[i * 64 + lane];
#pragma unroll
    for (int i = 0; i < 4; ++i) bf2[i] = wf2[i * 64 + lane];
    const uint4* tab = (const uint4*)(wsb + TABO_B);

    f32x4 a2[2];
    mlp_tile<3>(w, lane, tab, bf1, bf2, biasf, 192, 256, arena, hlds[w], a2);
    int rb = w * 16 + q4;
#pragma unroll
    for (int nt = 0; nt < 2; ++nt) {
      int col = nt * 16 + cl;
      if (col < 24) {
        if (rb + 3 < 60) {
          atomicAdd(&osum[col], a2[nt][0] + a2[nt][1] + a2[nt][2] + a2[nt][3]);
        } else {
#pragma unroll
          for (int r = 0; r < 4; ++r) {
            if (rb + r < 60) atomicAdd(&osum[col], a2[nt][r]);
          }
        }
      }
    }
  }

  __syncthreads();
  if (tid == 0) {
    float sd = Bc[0];
#pragma unroll
    for (int o = 0; o < 24; ++o) sd = fmaf(osum[o], Wc[o], sd);
    out[b] = 1.f / (1.f + expf(-sd));
  }
}

extern "C" void kernel_launch(void* const* d_in, const int* in_sizes, int n_in,
                              void* d_out, int out_size, void* d_ws, size_t ws_size,
                              hipStream_t stream) {
  const float* x     = (const float*)d_in[0];
  const float* y     = (const float*)d_in[1];
  const float* W1_pp = (const float*)d_in[2];
  const float* b1_pp = (const float*)d_in[3];
  const float* W2_pp = (const float*)d_in[4];
  const float* b2_pp = (const float*)d_in[5];
  const float* W1_pv = (const float*)d_in[6];
  const float* b1_pv = (const float*)d_in[7];
  const float* W2_pv = (const float*)d_in[8];
  const float* b2_pv = (const float*)d_in[9];
  const float* W1_o  = (const float*)d_in[10];
  const float* b1_o  = (const float*)d_in[11];
  const float* W2_o  = (const float*)d_in[12];
  const float* b2_o  = (const float*)d_in[13];
  const float* Wc    = (const float*)d_in[14];
  const float* bc    = (const float*)d_in[15];
  float* out = (float*)d_out;
  char* wsb = (char*)d_ws;

  const int Bb = in_sizes[0] / 3600;  // 1024
  const int tab_total = NTAB_PP + NTAB_PV + NTAB_O;  // 542208

  build_tables<<<(tab_total + 255) / 256, 256, 0, stream>>>(wsb);
  build_wfrag<<<(13600 + 255) / 256, 256, 0, stream>>>(wsb,
      W1_pp, W2_pp, W1_pv, W2_pv, W1_o, W2_o,
      b1_pp, b2_pp, b1_pv, b2_pv, b1_o, b2_o);
  fused_kernel<<<Bb, 256, 0, stream>>>(x, y, Wc, bc, wsb, out);
}